// Round 6
// baseline (109.033 us; speedup 1.0000x reference)
//
#include <hip/hip_runtime.h>
#include <hip/hip_bf16.h>

#define B_   8
#define N_   128
#define H_   768
#define HID_ 384
#define L_   100

typedef float f32x4 __attribute__((ext_vector_type(4)));
typedef short s16x8 __attribute__((ext_vector_type(8)));

__device__ __forceinline__ short f2bf(float f) {
    __hip_bfloat16 h = __float2bfloat16(f);
    return __builtin_bit_cast(short, h);
}

// async global->LDS, 16 B per lane. LDS dest = wave-uniform base (+lane*16 by HW);
// global src is per-lane.
__device__ __forceinline__ void gl_lds16(const void* g, void* l) {
    __builtin_amdgcn_global_load_lds(
        (const __attribute__((address_space(1))) unsigned int*)g,
        (__attribute__((address_space(3))) unsigned int*)l, 16, 0, 0);
}

// ---------------------------------------------------------------------------
// Merged prep: blocks [0,288) -> W1f, blocks [288,309) -> W2f.
// W1f[ct 0..47][kk 0..23][lane][e]: col c = ct*16+(lane&15), k = kk*32+(lane>>4)*8+e
// W2f[kk 0..11][t 0..6][lane][e], L padded to 112.
// ---------------------------------------------------------------------------
__global__ void prep_weights(const float* __restrict__ W1, const float* __restrict__ W2,
                             short* __restrict__ W1f, short* __restrict__ W2f) {
    if (blockIdx.x < 288) {
        int tid  = blockIdx.x * 256 + threadIdx.x;        // < 48*24*64 exactly
        int lane = tid & 63;
        int kk   = (tid >> 6) % 24;
        int ct   = tid / (24 * 64);
        int c    = ct * 16 + (lane & 15);
        int k0   = kk * 32 + ((lane >> 4) << 3);
        short v[8];
#pragma unroll
        for (int e = 0; e < 8; ++e) {
            int k = k0 + e;
            float f = (c < HID_) ? W1[(size_t)k * HID_ + c]
                                 : W1[(size_t)(H_ + k) * HID_ + (c - HID_)];
            v[e] = f2bf(f);
        }
        ((s16x8*)W1f)[tid] = *(const s16x8*)v;
    } else {
        int tid  = (blockIdx.x - 288) * 256 + threadIdx.x; // < 12*7*64 exactly
        int lane = tid & 63;
        int t    = (tid >> 6) % 7;
        int kk   = tid / (7 * 64);
        int c    = t * 16 + (lane & 15);
        int k0   = kk * 32 + ((lane >> 4) << 3);
        short v[8];
#pragma unroll
        for (int e = 0; e < 8; ++e) {
            float f = (c < L_) ? W2[(size_t)(k0 + e) * L_ + c] : 0.0f;
            v[e] = f2bf(f);
        }
        ((s16x8*)W2f)[tid] = *(const s16x8*)v;
    }
}

// ---------------------------------------------------------------------------
// pq_gemm: P(+b1) and Q from repr @ W1, MFMA. A staged to LDS via gl_lds.
// P written TRANSPOSED: Pt[b][slice 0..11][u 0..7][row 0..127][e4 0..3]
// (16 KB contiguous per slice) so fused_out gets coalesced direct loads.
// Q row-major [1024][384]. Grid 768 = rt(64) x cg(12).
// ---------------------------------------------------------------------------
__global__ __launch_bounds__(256) void pq_gemm(
    const float* __restrict__ repr, const short* __restrict__ W1f,
    const float* __restrict__ b1,
    float* __restrict__ Pt, float* __restrict__ Q)
{
    __shared__ float atile[192 * 16 * 4];   // 49152 B
    const int rt   = blockIdx.x / 12;
    const int cg   = blockIdx.x % 12;
    const int w    = threadIdx.x >> 6;
    const int lane = threadIdx.x & 63;
    const int l15  = lane & 15;
    const int g    = lane >> 4;
    const int ct   = cg * 4 + w;
    const int row_g0 = rt * 16;

#pragma unroll
    for (int c = 0; c < 12; ++c) {
        int call = w * 12 + c;
        const float* src = repr + (size_t)(row_g0 + (lane & 15)) * H_
                         + (call * 4 + (lane >> 4)) * 4;
        gl_lds16(src, (char*)atile + call * 1024);
    }
    __syncthreads();

    f32x4 acc;
    acc[0] = 0.f; acc[1] = 0.f; acc[2] = 0.f; acc[3] = 0.f;
    const s16x8* bbase = (const s16x8*)W1f + (size_t)(ct * 24) * 64 + lane;

    s16x8 lb = bbase[0];                    // 1-deep W1f prefetch
#pragma unroll
    for (int kk = 0; kk < 24; ++kk) {
        s16x8 bf = lb;
        if (kk < 23) lb = bbase[(size_t)(kk + 1) * 64];
        const int u0 = kk * 8 + g * 2;
        float a[8];
        *(float4*)&a[0] = *(const float4*)&atile[(u0 * 16 + l15) * 4];
        *(float4*)&a[4] = *(const float4*)&atile[((u0 + 1) * 16 + l15) * 4];
        s16x8 af;
#pragma unroll
        for (int e = 0; e < 8; ++e) af[e] = f2bf(a[e]);
        acc = __builtin_amdgcn_mfma_f32_16x16x32_bf16(af, bf, acc, 0, 0, 0);
    }

    const int b = rt >> 3;
    const int c = ct * 16 + l15;
#pragma unroll
    for (int r = 0; r < 4; ++r) {
        int brow = (rt & 7) * 16 + g * 4 + r;
        float v = acc[r];
        if (c < HID_) {
            int slice = c >> 5, un = (c & 31) >> 2, e4 = c & 3;
            Pt[((((size_t)b * 12 + slice) * 8 + un) * 128 + brow) * 4 + e4] = v + b1[c];
        } else {
            Q[(size_t)(b * N_ + brow) * HID_ + (c - HID_)] = v;
        }
    }
}

// ---------------------------------------------------------------------------
// fused_out: out[b,i,j,l] = relu(P[b,j,:]+Q[b,i,:]) . W2 + b2
// Grid 512: blk -> (b = blk>>6, i0 = (blk&63)*2). 512 thr = 8 waves; wave w
// owns j in [w*16, +16), 2 i each, 7 L-tiles.
// Prologue: stage ALL W2f (84 KB) + 2 Q rows (3 KB) into LDS, one barrier.
// Main loop: BARRIER-FREE. Pt read directly from global -- the transposed
// layout makes lane loads 256B-contiguous per 16-lane group (coalesced).
// W2f from LDS ds_read_b128 (linear, conflict-free); Q from LDS (broadcast).
// Epilogue: barrier, overlay acc into LDS (stride 114), coalesced row stores.
// ---------------------------------------------------------------------------
__global__ __launch_bounds__(512, 2) void fused_out(
    const float* __restrict__ Pt, const float* __restrict__ Q,
    const short* __restrict__ W2f, const float* __restrict__ b2,
    float* __restrict__ out)
{
    __shared__ __align__(16) char smem[89088];   // 84K W2f + 3K Q
    const s16x8* w2s = (const s16x8*)smem;       // [84 chunks][64 lanes]
    const float* qF  = (const float*)(smem + 86016);
    float* storeF    = (float*)smem;             // epilogue overlay (58368 B)

    const int blk  = blockIdx.x;
    const int b    = blk >> 6;
    const int i0   = (blk & 63) << 1;
    const int w    = threadIdx.x >> 6;
    const int lane = threadIdx.x & 63;
    const int l15  = lane & 15;
    const int g    = lane >> 4;

    // ---- prologue: stage W2f (84 calls of 1 KB) + Q (3 calls) ----
#pragma unroll
    for (int c = 0; c < 11; ++c) {
        int call = w * 11 + c;
        if (call < 84)
            gl_lds16((const char*)W2f + call * 1024 + lane * 16,
                     (char*)smem + call * 1024);
    }
    if (w == 7) {
        const char* qsrc = (const char*)(Q + (size_t)(b * N_ + i0) * HID_);
#pragma unroll
        for (int c2 = 0; c2 < 3; ++c2)
            gl_lds16(qsrc + c2 * 1024 + lane * 16, (char*)smem + 86016 + c2 * 1024);
    }
    __syncthreads();

    f32x4 acc[2][7];
#pragma unroll
    for (int ii = 0; ii < 2; ++ii)
#pragma unroll
        for (int t = 0; t < 7; ++t) {
            acc[ii][t][0] = 0.f; acc[ii][t][1] = 0.f;
            acc[ii][t][2] = 0.f; acc[ii][t][3] = 0.f;
        }

    // Pt direct-load addresses (coalesced: 16 lanes x 16 B contiguous per g)
    const char* ptb = (const char*)Pt + (size_t)b * 12 * 16384;
    const char* pt0 = ptb + (((g * 2 + 0) * 128) + w * 16 + l15) * 16;
    const char* pt1 = ptb + (((g * 2 + 1) * 128) + w * 16 + l15) * 16;

    float4 lp0 = *(const float4*)pt0;       // 1-deep prefetch
    float4 lp1 = *(const float4*)pt1;

#pragma unroll
    for (int kk = 0; kk < 12; ++kk) {
        float p[8];
        *(float4*)&p[0] = lp0;
        *(float4*)&p[4] = lp1;
        if (kk < 11) {
            lp0 = *(const float4*)(pt0 + (size_t)(kk + 1) * 16384);
            lp1 = *(const float4*)(pt1 + (size_t)(kk + 1) * 16384);
        }

        float q0v[8], q1v[8];
        *(float4*)&q0v[0] = *(const float4*)&qF[0 * HID_ + kk * 32 + g * 8];
        *(float4*)&q0v[4] = *(const float4*)&qF[0 * HID_ + kk * 32 + g * 8 + 4];
        *(float4*)&q1v[0] = *(const float4*)&qF[1 * HID_ + kk * 32 + g * 8];
        *(float4*)&q1v[4] = *(const float4*)&qF[1 * HID_ + kk * 32 + g * 8 + 4];

        s16x8 af0, af1;
#pragma unroll
        for (int e = 0; e < 8; ++e) {
            af0[e] = f2bf(fmaxf(p[e] + q0v[e], 0.f));
            af1[e] = f2bf(fmaxf(p[e] + q1v[e], 0.f));
        }

        const s16x8* bfp = w2s + (size_t)(kk * 7) * 64 + lane;
#pragma unroll
        for (int t = 0; t < 7; ++t) {
            s16x8 bf = bfp[(size_t)t * 64];
            acc[0][t] = __builtin_amdgcn_mfma_f32_16x16x32_bf16(af0, bf, acc[0][t], 0, 0, 0);
            acc[1][t] = __builtin_amdgcn_mfma_f32_16x16x32_bf16(af1, bf, acc[1][t], 0, 0, 0);
        }
    }

    // ---- epilogue: bias, LDS transpose (wave-private), coalesced stores ----
    float bias[7];
#pragma unroll
    for (int t = 0; t < 7; ++t) {
        int l = t * 16 + l15;
        bias[t] = (l < L_) ? b2[l] : 0.f;
    }

    __syncthreads();   // everyone done reading w2s/qF; reuse as store staging
    float* srow = storeF + w * (16 * 114);

#pragma unroll
    for (int ii = 0; ii < 2; ++ii) {
#pragma unroll
        for (int t = 0; t < 7; ++t)
#pragma unroll
            for (int r = 0; r < 4; ++r)
                srow[(g * 4 + r) * 114 + t * 16 + l15] = acc[ii][t][r] + bias[t];
        // wave-private region: ds ordering via lgkmcnt, no barrier needed
        const size_t obase = (size_t)(b * N_ + (i0 + ii)) * N_ * L_;
#pragma unroll
        for (int row = 0; row < 16; ++row) {
            if (lane < 50) {
                float2 v = *(const float2*)&srow[row * 114 + lane * 2];
                *(float2*)(out + obase + (size_t)(w * 16 + row) * L_ + lane * 2) = v;
            }
        }
    }
}

// ---------------------------------------------------------------------------
extern "C" void kernel_launch(void* const* d_in, const int* in_sizes, int n_in,
                              void* d_out, int out_size, void* d_ws, size_t ws_size,
                              hipStream_t stream)
{
    const float* repr = (const float*)d_in[0];
    const float* W1   = (const float*)d_in[1];
    const float* b1   = (const float*)d_in[2];
    const float* W2   = (const float*)d_in[3];
    const float* b2   = (const float*)d_in[4];
    float* out = (float*)d_out;

    char* ws = (char*)d_ws;
    float* Pt  = (float*)(ws);                         // 1572864 B (transposed layout)
    float* Qm  = (float*)(ws + 1572864);               // 1572864 B
    short* W1f = (short*)(ws + 3145728);               // 1179648 B
    short* W2f = (short*)(ws + 4325376);               // 86016 B

    hipLaunchKernelGGL(prep_weights, dim3(309), dim3(256), 0, stream, W1, W2, W1f, W2f);
    hipLaunchKernelGGL(pq_gemm,      dim3(768), dim3(256), 0, stream, repr, W1f, b1, Pt, Qm);
    hipLaunchKernelGGL(fused_out,    dim3(512), dim3(512), 0, stream, Pt, Qm, W2f, b2, out);
}